// Round 10
// baseline (163.643 us; speedup 1.0000x reference)
//
#include <hip/hip_runtime.h>

#define N_NODES 100000
#define N_EDGES 1600000
#define HID 150
#define KPAD 160
#define OUTF 64
#define BSH 9                          // 512 nodes per bucket
#define BUKN 512                       // nodes per bucket
#define NBUK ((N_NODES + BUKN - 1) / BUKN)   // 196 buckets
#define TILE 4096                      // edges per partition tile
#define NTILE ((N_EDGES + TILE - 1) / TILE)  // 391 tiles

typedef short bf16x8 __attribute__((ext_vector_type(8)));
typedef float f32x4 __attribute__((ext_vector_type(4)));

__device__ __forceinline__ unsigned short f2bf(float f) {
    union { float f; unsigned u; } v; v.f = f;
    unsigned r = (v.u + 0x7FFFu + ((v.u >> 16) & 1u)) >> 16;
    return (unsigned short)r;
}

__device__ __forceinline__ float bf2f(unsigned short b) {
    union { unsigned u; float f; } v;
    v.u = ((unsigned)b) << 16;
    return v.f;
}

// ---------------- prep: pad x -> x4, bucket histogram of dst, W1t/W2T pack ----------------
__global__ __launch_bounds__(256) void k_prep(const float* __restrict__ x,
                                              float4* __restrict__ x4,
                                              const int* __restrict__ dst,
                                              int* __restrict__ bukcnt,
                                              const float* __restrict__ W1s,
                                              const float* __restrict__ W1n,
                                              const float* __restrict__ b1,
                                              const float* __restrict__ W2s,
                                              const float* __restrict__ W2n,
                                              float* __restrict__ W1t,
                                              unsigned short* __restrict__ W2T) {
    __shared__ int cnt[NBUK];
    int tid = threadIdx.x;
    for (int i = tid; i < NBUK; i += 256) cnt[i] = 0;
    int idx = blockIdx.x * 256 + tid;
    if (idx < N_NODES)
        x4[idx] = make_float4(x[idx * 3 + 0], x[idx * 3 + 1], x[idx * 3 + 2], 0.0f);
    if (idx < KPAD) {
        int k = idx;
        bool ok = (k < HID);
        W1t[k * 8 + 0] = ok ? W1s[0 * HID + k] : 0.0f;
        W1t[k * 8 + 1] = ok ? W1s[1 * HID + k] : 0.0f;
        W1t[k * 8 + 2] = ok ? W1s[2 * HID + k] : 0.0f;
        W1t[k * 8 + 3] = ok ? b1[k] : 0.0f;
        W1t[k * 8 + 4] = ok ? W1n[0 * HID + k] : 0.0f;
        W1t[k * 8 + 5] = ok ? W1n[1 * HID + k] : 0.0f;
        W1t[k * 8 + 6] = ok ? W1n[2 * HID + k] : 0.0f;
        W1t[k * 8 + 7] = 0.0f;
    }
    if (idx < 128 * KPAD) {
        int c = idx / KPAD, k = idx - c * KPAD;
        float v = 0.0f;
        if (k < HID) v = (c < 64) ? W2s[k * 64 + c] : W2n[k * 64 + (c - 64)];
        W2T[idx] = f2bf(v);
    }
    __syncthreads();
    int e0 = blockIdx.x * TILE;
    #pragma unroll
    for (int j = 0; j < 16; ++j) {
        int e = e0 + tid + j * 256;
        if (e < N_EDGES) atomicAdd(&cnt[dst[e] >> BSH], 1);
    }
    __syncthreads();
    for (int i = tid; i < NBUK; i += 256)
        if (cnt[i]) atomicAdd(&bukcnt[i], cnt[i]);
}

// ---------------- bucket scan: bukcnt -> bukoff (exclusive), zero bukcur ----------------
__global__ __launch_bounds__(256) void k_bukscan(const int* __restrict__ bukcnt,
                                                 int* __restrict__ bukoff,
                                                 int* __restrict__ bukcur,
                                                 int* __restrict__ row_start) {
    __shared__ int sh[256];
    int t = threadIdx.x;
    int v = (t < NBUK) ? bukcnt[t] : 0;
    sh[t] = v;
    __syncthreads();
    for (int o = 1; o < 256; o <<= 1) {
        int a = sh[t];
        int ap = (t >= o) ? sh[t - o] : 0;
        __syncthreads();
        sh[t] = a + ap;
        __syncthreads();
    }
    if (t < NBUK) { bukoff[t] = sh[t] - v; bukcur[t] = 0; }
    if (t == 255) {
        bukoff[NBUK] = sh[NBUK - 1];
        row_start[N_NODES] = sh[NBUK - 1];
    }
}

// ---------------- multisplit partition: direct bucket-segment writes ----------------
__global__ __launch_bounds__(256) void k_part(const int* __restrict__ src,
                                              const int* __restrict__ dst,
                                              const int* __restrict__ bukoff,
                                              int* __restrict__ bukcur,
                                              unsigned int* __restrict__ pairbuf) {
    __shared__ int cnt[NBUK];
    __shared__ int gbase[NBUK];
    int tid = threadIdx.x;
    int e0 = blockIdx.x * TILE;
    int n = min(TILE, N_EDGES - e0);

    for (int i = tid; i < NBUK; i += 256) cnt[i] = 0;
    __syncthreads();

    int myb[16];
    int mypos[16];
    unsigned int myv[16];
    #pragma unroll
    for (int j = 0; j < 16; ++j) {
        int idx = tid + j * 256;
        myb[j] = -1;
        if (idx < n) {
            int s = src[e0 + idx];
            int d = dst[e0 + idx];
            int b = d >> BSH;
            myb[j] = b;
            myv[j] = ((unsigned int)(d & (BUKN - 1)) << 17) | (unsigned int)s;
            mypos[j] = atomicAdd(&cnt[b], 1);
        }
    }
    __syncthreads();

    if (tid < NBUK) {
        int c = cnt[tid];
        gbase[tid] = c ? (bukoff[tid] + atomicAdd(&bukcur[tid], c)) : 0;
    }
    __syncthreads();

    #pragma unroll
    for (int j = 0; j < 16; ++j) {
        if (myb[j] >= 0)
            pairbuf[gbase[myb[j]] + mypos[j]] = myv[j];
    }
}

// ---------------- merged per-bucket CSR finish: hist + scan + row_start/invd + scatter --
__global__ __launch_bounds__(256) void k_fine(const int* __restrict__ bukoff,
                                              const unsigned int* __restrict__ pairbuf,
                                              int* __restrict__ row_start,
                                              float* __restrict__ invd,
                                              int* __restrict__ csr_src) {
    __shared__ int deg[BUKN];      // counts, later reused as scatter cursors
    __shared__ int scan[256];
    int tid = threadIdx.x;
    int b = blockIdx.x;
    int n0 = b << BSH;
    int lo = bukoff[b], hi = bukoff[b + 1];

    for (int i = tid; i < BUKN; i += 256) deg[i] = 0;
    __syncthreads();
    for (int i = lo + tid; i < hi; i += 256)
        atomicAdd(&deg[pairbuf[i] >> 17], 1);
    __syncthreads();

    int d0 = deg[2 * tid], d1 = deg[2 * tid + 1];
    int pairsum = d0 + d1;
    scan[tid] = pairsum;
    __syncthreads();
    for (int o = 1; o < 256; o <<= 1) {
        int a = scan[tid];
        int ap = (tid >= o) ? scan[tid - o] : 0;
        __syncthreads();
        scan[tid] = a + ap;
        __syncthreads();
    }
    int r0 = lo + scan[tid] - pairsum;
    int r1 = r0 + d0;
    int node0 = n0 + 2 * tid, node1 = node0 + 1;
    if (node0 < N_NODES) { row_start[node0] = r0; invd[node0] = 1.0f / fmaxf((float)d0, 1.0f); }
    if (node1 < N_NODES) { row_start[node1] = r1; invd[node1] = 1.0f / fmaxf((float)d1, 1.0f); }
    __syncthreads();
    deg[2 * tid] = r0;
    deg[2 * tid + 1] = r1;
    __syncthreads();
    for (int i = lo + tid; i < hi; i += 256) {
        unsigned int v = pairbuf[i];
        int dl = v >> 17;
        int ofs = atomicAdd(&deg[dl], 1);
        csr_src[ofs] = (int)(v & 0x1FFFF);
    }
}

// ---------------- layer-1 neighbor mean ----------------

__global__ void k_agg1(const int* __restrict__ row_start, const int* __restrict__ csr_src,
                       const float4* __restrict__ x4, const float* __restrict__ invd,
                       float4* __restrict__ hn4) {
    int wid = (blockIdx.x * blockDim.x + threadIdx.x) >> 6;
    int lane = threadIdx.x & 63;
    int n = wid * 16 + (lane >> 2);
    if (n >= N_NODES) return;
    int sub = lane & 3;
    int b = row_start[n], e = row_start[n + 1];
    float s0 = 0.f, s1 = 0.f, s2 = 0.f;
    for (int i = b + sub; i < e; i += 4) {
        float4 v = x4[csr_src[i]];
        s0 += v.x; s1 += v.y; s2 += v.z;
    }
    s0 += __shfl_xor(s0, 1, 64); s0 += __shfl_xor(s0, 2, 64);
    s1 += __shfl_xor(s1, 1, 64); s1 += __shfl_xor(s1, 2, 64);
    s2 += __shfl_xor(s2, 1, 64); s2 += __shfl_xor(s2, 2, 64);
    if (sub == 0) {
        float id = invd[n];
        hn4[n] = make_float4(s0 * id, s1 * id, s2 * id, 0.0f);
    }
}

// ---------------- fused layer1 + layer2 GEMM via bf16 MFMA ----------------
// Writes one bf16 row per node: ob[node][0..63] = self+b2, ob[node][64..127] = p
#define SHK 168
__global__ __launch_bounds__(256, 4) void k_gemm(
        const float4* __restrict__ x4, const float4* __restrict__ hn4,
        const float* __restrict__ W1t,
        const unsigned short* __restrict__ W2T,
        const float* __restrict__ b2,
        unsigned short* __restrict__ ob) {
    __shared__ unsigned short shA[64 * SHK];   // 21.5 KB
    const int n0 = blockIdx.x * 64;
    const int tid = threadIdx.x;

    {
        int n = tid & 63;
        int node = n0 + n;
        int kbase = 2 * (tid >> 6);
        float4 xs = make_float4(0.f, 0.f, 0.f, 0.f);
        float4 xn = make_float4(0.f, 0.f, 0.f, 0.f);
        if (node < N_NODES) { xs = x4[node]; xn = hn4[node]; }
        #pragma unroll 4
        for (int j = 0; j < 20; ++j) {
            int k = kbase + 8 * j;
            float4 wa0 = *(const float4*)&W1t[k * 8 + 0];
            float4 wb0 = *(const float4*)&W1t[k * 8 + 4];
            float4 wa1 = *(const float4*)&W1t[(k + 1) * 8 + 0];
            float4 wb1 = *(const float4*)&W1t[(k + 1) * 8 + 4];
            float h0 = wa0.w + xs.x * wa0.x + xs.y * wa0.y + xs.z * wa0.z
                             + xn.x * wb0.x + xn.y * wb0.y + xn.z * wb0.z;
            float h1 = wa1.w + xs.x * wa1.x + xs.y * wa1.y + xs.z * wa1.z
                             + xn.x * wb1.x + xn.y * wb1.y + xn.z * wb1.z;
            h0 = fmaxf(h0, 0.0f);
            h1 = fmaxf(h1, 0.0f);
            unsigned int pk = (unsigned int)f2bf(h0) | ((unsigned int)f2bf(h1) << 16);
            *(unsigned int*)&shA[n * SHK + k] = pk;
        }
    }
    __syncthreads();

    const int lane = tid & 63;
    const int w = tid >> 6;
    const int c16 = lane & 15;
    const int quad = lane >> 4;
    const int ko = quad * 8;

    f32x4 acc[8];
    #pragma unroll
    for (int t = 0; t < 8; ++t) acc[t] = (f32x4){0.f, 0.f, 0.f, 0.f};

    #pragma unroll
    for (int ks = 0; ks < 5; ++ks) {
        int k0 = ks * 32;
        bf16x8 a = *(const bf16x8*)&shA[(w * 16 + c16) * SHK + k0 + ko];
        #pragma unroll
        for (int t = 0; t < 8; ++t) {
            bf16x8 b = *(const bf16x8*)&W2T[(t * 16 + c16) * KPAD + k0 + ko];
            acc[t] = __builtin_amdgcn_mfma_f32_16x16x32_bf16(a, b, acc[t], 0, 0, 0);
        }
    }

    const int rbase = n0 + w * 16 + quad * 4;
    #pragma unroll
    for (int t = 0; t < 8; ++t) {
        int cc = t * 16 + c16;
        float badd = (t < 4) ? b2[cc] : 0.0f;
        #pragma unroll
        for (int i = 0; i < 4; ++i) {
            int node = rbase + i;
            if (node < N_NODES) ob[(size_t)node * 128 + cc] = f2bf(acc[t][i] + badd);
        }
    }
}

// ---------------- layer-2 pull: batched index load + shuffle-broadcast gathers ----------
// 1 wave/node. Lanes: g = lane>>3 (edge slot group), c = lane&7 (col chunk).
// One coalesced csr load covers 64 edges; 8 unrolled rounds of INDEPENDENT gathers.
__global__ void k_pull(const int* __restrict__ row_start, const int* __restrict__ csr_src,
                       const unsigned short* __restrict__ ob, const float* __restrict__ invd,
                       float* __restrict__ out) {
    int n = blockIdx.x * 4 + (threadIdx.x >> 6);
    if (n >= N_NODES) return;
    int lane = threadIdx.x & 63;
    int g = lane >> 3;
    int c = lane & 7;
    int b = row_start[n], e = row_start[n + 1];
    float acc[8];
    #pragma unroll
    for (int q = 0; q < 8; ++q) acc[q] = 0.0f;

    for (int base = b; base < e; base += 64) {
        int nv = e - base;                       // edges in this batch (may exceed 64)
        int idx = 0;
        if (lane < nv) idx = csr_src[base + lane];
        #pragma unroll
        for (int r = 0; r < 8; ++r) {
            int ei = r * 8 + g;
            int s = __shfl(idx, ei, 64);
            if (ei < nv) {
                bf16x8 v = *(const bf16x8*)&ob[(size_t)s * 128 + 64 + c * 8];
                #pragma unroll
                for (int q = 0; q < 8; ++q) acc[q] += bf2f((unsigned short)v[q]);
            }
        }
    }

    #pragma unroll
    for (int q = 0; q < 8; ++q) {
        acc[q] += __shfl_xor(acc[q], 8, 64);
        acc[q] += __shfl_xor(acc[q], 16, 64);
        acc[q] += __shfl_xor(acc[q], 32, 64);
    }
    if (g == 0) {
        float id = invd[n];
        bf16x8 sv = *(const bf16x8*)&ob[(size_t)n * 128 + c * 8];
        float4 o0, o1;
        o0.x = bf2f((unsigned short)sv[0]) + acc[0] * id;
        o0.y = bf2f((unsigned short)sv[1]) + acc[1] * id;
        o0.z = bf2f((unsigned short)sv[2]) + acc[2] * id;
        o0.w = bf2f((unsigned short)sv[3]) + acc[3] * id;
        o1.x = bf2f((unsigned short)sv[4]) + acc[4] * id;
        o1.y = bf2f((unsigned short)sv[5]) + acc[5] * id;
        o1.z = bf2f((unsigned short)sv[6]) + acc[6] * id;
        o1.w = bf2f((unsigned short)sv[7]) + acc[7] * id;
        *(float4*)&out[(size_t)n * OUTF + c * 8]     = o0;
        *(float4*)&out[(size_t)n * OUTF + c * 8 + 4] = o1;
    }
}

// ---------------- launcher ----------------

static inline size_t al256(size_t v) { return (v + 255) & ~(size_t)255; }

extern "C" void kernel_launch(void* const* d_in, const int* in_sizes, int n_in,
                              void* d_out, int out_size, void* d_ws, size_t ws_size,
                              hipStream_t stream) {
    const float* x   = (const float*)d_in[0];
    const int*   src = (const int*)d_in[1];
    const int*   dst = (const int*)d_in[2];
    const float* W1s = (const float*)d_in[3];
    const float* W1n = (const float*)d_in[4];
    const float* b1  = (const float*)d_in[5];
    const float* W2s = (const float*)d_in[6];
    const float* W2n = (const float*)d_in[7];
    const float* b2  = (const float*)d_in[8];
    float* out = (float*)d_out;

    char* ws = (char*)d_ws;
    size_t off = 0;
    int*   row_start = (int*)(ws + off); off += al256((size_t)(N_NODES + 1) * 4);
    int*   csr_src   = (int*)(ws + off); off += al256((size_t)N_EDGES * 4);
    float* invd      = (float*)(ws + off); off += al256((size_t)N_NODES * 4);
    unsigned short* ob = (unsigned short*)(ws + off); off += al256((size_t)N_NODES * 128 * 2);
    float4* x4       = (float4*)(ws + off); off += al256((size_t)N_NODES * 16);
    float4* hn4      = (float4*)(ws + off); off += al256((size_t)N_NODES * 16);
    unsigned int* pairbuf = (unsigned int*)(ws + off); off += al256((size_t)N_EDGES * 4);
    int*   bukcnt    = (int*)(ws + off); off += al256((size_t)NBUK * 4);
    int*   bukoff    = (int*)(ws + off); off += al256((size_t)(NBUK + 1) * 4);
    int*   bukcur    = (int*)(ws + off); off += al256((size_t)NBUK * 4);
    float* W1t       = (float*)(ws + off); off += al256((size_t)KPAD * 8 * 4);
    unsigned short* W2T = (unsigned short*)(ws + off); off += al256((size_t)128 * KPAD * 2);

    hipMemsetAsync(bukcnt, 0, (size_t)NBUK * 4, stream);

    k_prep<<<NTILE, 256, 0, stream>>>(x, x4, dst, bukcnt, W1s, W1n, b1, W2s, W2n, W1t, W2T);
    k_bukscan<<<1, 256, 0, stream>>>(bukcnt, bukoff, bukcur, row_start);
    k_part<<<NTILE, 256, 0, stream>>>(src, dst, bukoff, bukcur, pairbuf);
    k_fine<<<NBUK, 256, 0, stream>>>(bukoff, pairbuf, row_start, invd, csr_src);
    {   // layer-1 neighbor mean
        int waves = (N_NODES + 15) / 16;
        int blocks = (waves * 64 + 255) / 256;
        k_agg1<<<blocks, 256, 0, stream>>>(row_start, csr_src, x4, invd, hn4);
    }
    {   // fused layer1+layer2 GEMM (bf16 MFMA) -> unified bf16 row buffer
        int blocks = (N_NODES + 63) / 64;
        k_gemm<<<blocks, 256, 0, stream>>>(x4, hn4, W1t, W2T, b2, ob);
    }
    {   // layer-2 neighbor aggregation (pull, batched-index)
        int blocks = (N_NODES + 3) / 4;
        k_pull<<<blocks, 256, 0, stream>>>(row_start, csr_src, ob, invd, out);
    }
}